// Round 6
// baseline (148.919 us; speedup 1.0000x reference)
//
#include <hip/hip_runtime.h>
#include <math.h>

#define NUM_TOKENS 16384
#define NUM_HEADS  32
#define HEAD_SIZE  128
#define TOTAL_PAIRS (NUM_TOKENS * NUM_HEADS)   // 524288
#define NTHREADS 256

typedef float vfloat4 __attribute__((ext_vector_type(4)));

// Best measured structure (round 1, 140.3 us): one 32-lane sub-group per
// (token, head) pair, token-major. Each wave instruction touches a single
// fully-contiguous 1KB segment per stream (32 lanes x float4). Per-group
// LSE math is recomputed per lane (broadcast loads; L2/L3-resident 2MB
// arrays); lane 0 writes the merged LSE.
//
// Roofline note: 774MB app-level traffic at 140us = 5.53 TB/s blended
// (88% of the 6.29 TB/s copy ceiling); read direction alone = 3.69 TB/s,
// above the 1:1 copy bench's per-direction rate. A pure-stream variant with
// zero VALU overhead (round 4) ties this kernel => memory-path-bound.
__global__ __launch_bounds__(NTHREADS) void merge_attn_states_kernel(
    const float* __restrict__ p_out,   // [NUM_TOKENS, NUM_HEADS, HEAD_SIZE]
    const float* __restrict__ p_lse,   // [NUM_HEADS, NUM_TOKENS]
    const float* __restrict__ s_out,   // [NUM_TOKENS, NUM_HEADS, HEAD_SIZE]
    const float* __restrict__ s_lse,   // [NUM_HEADS, NUM_TOKENS]
    float* __restrict__ out,           // [NUM_TOKENS, NUM_HEADS, HEAD_SIZE]
    float* __restrict__ out_lse)       // [NUM_HEADS, NUM_TOKENS]
{
    const int pair = blockIdx.x * 8 + (threadIdx.x >> 5);  // token*32 + head
    const int lane = threadIdx.x & 31;
    const int head  = pair & (NUM_HEADS - 1);
    const int token = pair >> 5;  // log2(NUM_HEADS) = 5
    const int lse_idx = head * NUM_TOKENS + token;

    // Issue the streaming loads first so they overlap the LSE chain.
    const size_t base = (size_t)pair * HEAD_SIZE;
    const vfloat4* __restrict__ pv = reinterpret_cast<const vfloat4*>(p_out + base);
    const vfloat4* __restrict__ sv = reinterpret_cast<const vfloat4*>(s_out + base);
    vfloat4 a = pv[lane];
    vfloat4 b = sv[lane];

    float pl = p_lse[lse_idx];
    float sl = s_lse[lse_idx];
    // +inf -> -inf sanitization (matches vLLM merge_attn_states)
    pl = (pl == INFINITY) ? -INFINITY : pl;
    sl = (sl == INFINITY) ? -INFINITY : sl;

    const float m  = fmaxf(pl, sl);
    const float pe = __expf(pl - m);
    const float se = __expf(sl - m);
    const float d  = pe + se;
    const float inv = __builtin_amdgcn_rcpf(d);
    const float ps = pe * inv;
    const float ss = se * inv;

    if (lane == 0) {
        out_lse[lse_idx] = __logf(d) + m;
    }

    vfloat4 r;
    r.x = fmaf(a.x, ps, b.x * ss);
    r.y = fmaf(a.y, ps, b.y * ss);
    r.z = fmaf(a.z, ps, b.z * ss);
    r.w = fmaf(a.w, ps, b.w * ss);
    reinterpret_cast<vfloat4*>(out + base)[lane] = r;
}

extern "C" void kernel_launch(void* const* d_in, const int* in_sizes, int n_in,
                              void* d_out, int out_size, void* d_ws, size_t ws_size,
                              hipStream_t stream) {
    const float* p_out = (const float*)d_in[0];  // prefix_output
    const float* p_lse = (const float*)d_in[1];  // prefix_lse
    const float* s_out = (const float*)d_in[2];  // suffix_output
    const float* s_lse = (const float*)d_in[3];  // suffix_lse

    float* out     = (float*)d_out;
    float* out_lse = (float*)d_out + (size_t)NUM_TOKENS * NUM_HEADS * HEAD_SIZE;

    const int blocks = TOTAL_PAIRS / 8;   // 65536 blocks x 256 threads
    merge_attn_states_kernel<<<blocks, NTHREADS, 0, stream>>>(
        p_out, p_lse, s_out, s_lse, out, out_lse);
}